// Round 13
// baseline (430.052 us; speedup 1.0000x reference)
//
#include <hip/hip_runtime.h>

#define NN 100000
#define EE 1600000
#define CH 128
#define NG 512
#define OC 64

// coarse radix partition: 98 buckets of 1024 nodes; fixed-capacity staging cells
#define CSH 10
#define NCB 98
#define PBLK 256
#define PCHUNK 6250     // 256*6250 = 1.6M exactly
#define SCAP 128        // per (block,bucket) cell: mean 63.8 + 8 sigma

// workspace element offsets (4-byte units); total 110.4 MB
#define O_DINV   0
#define O_ROWS   100032   // 100001
#define O_CNT    200064   // 25088
#define O_PART   225152
#define O_OFFS   225280
#define O_START  225408   // 513
#define O_CSR    225984   // padded CSR, cap 2.50M words (sum pdeg <= 2.3M)
#define O_HS     2726016  // bf16 Hs: (NN+1) rows x 128 ushorts = 6400064 words
#define O_STG    9126080  // staging 3.21M words (dead after k_place)
#define O_WT1    9126080  // split W1: 32768 ushorts = 16384 words
#define O_WT2    9142464
#define O_A1     14800448 // fp32 A1: 12.8M words

typedef __attribute__((ext_vector_type(8))) short short8v;
typedef __attribute__((ext_vector_type(4))) float float4v;

static __device__ __forceinline__ unsigned short f2bf(float x) {
  unsigned u = __float_as_uint(x);
  return (unsigned short)((u + 0x7FFFu + ((u >> 16) & 1u)) >> 16);  // RNE
}
static __device__ __forceinline__ float bf2f(unsigned short h) {
  return __uint_as_float((unsigned)h << 16);
}
static __device__ __forceinline__ float bflo(unsigned v) {
  return __uint_as_float(v << 16);
}
static __device__ __forceinline__ float bfhi(unsigned v) {
  return __uint_as_float(v & 0xFFFF0000u);
}

// LDS radix scatter: hist -> scan -> ordered LDS buffer -> contiguous run copies.
__global__ __launch_bounds__(1024) void k_part(const int* __restrict__ src,
                                               const int* __restrict__ dst,
                                               int* __restrict__ cnt,
                                               unsigned* __restrict__ stg) {
  __shared__ int hist[NCB];   // counts, then exclusive bases
  __shared__ int lcur[NCB];
  __shared__ unsigned lout[PCHUNK];
  int t = threadIdx.x;
  int e0 = blockIdx.x * PCHUNK;
  if (t < NCB) { hist[t] = 0; lcur[t] = 0; }
  __syncthreads();
  for (int e = e0 + t; e < e0 + PCHUNK; e += 1024)
    atomicAdd(&hist[dst[e] >> CSH], 1);
  __syncthreads();
  if (t == 0) {
    int s = 0;
    for (int i = 0; i < NCB; ++i) { int v = hist[i]; hist[i] = s; s += v; }
  }
  __syncthreads();
  for (int e = e0 + t; e < e0 + PCHUNK; e += 1024) {
    int d = dst[e];
    int b = d >> CSH;
    int p = hist[b] + atomicAdd(&lcur[b], 1);
    lout[p] = (unsigned)src[e] | ((unsigned)(d & 1023) << 17);
  }
  __syncthreads();
  int w = t >> 6, lane = t & 63;
  unsigned* mystg = stg + (size_t)blockIdx.x * NCB * SCAP;
  for (int b = w; b < NCB; b += 16) {
    int beg = hist[b];
    int end = (b == NCB - 1) ? PCHUNK : hist[b + 1];
    int n = min(end - beg, SCAP);
    for (int i = lane; i < n; i += 64) mystg[b * SCAP + i] = lout[beg + i];
    if (lane == 0) cnt[blockIdx.x * NCB + b] = n;
  }
}

// Per bucket: degree histogram, dinv (real deg), exclusive scan of PADDED deg.
__global__ __launch_bounds__(1024) void k_count(const unsigned* __restrict__ stg,
                                                const int* __restrict__ cnt,
                                                int* __restrict__ rows,
                                                int* __restrict__ part,
                                                float* __restrict__ dinv) {
  __shared__ int ldeg[1024];
  __shared__ int s[1024];
  int b = blockIdx.x;
  int t = threadIdx.x;
  int w = t >> 6, lane = t & 63;
  int gid = (b << CSH) + t;
  ldeg[t] = 0;
  __syncthreads();
  for (int blk = w; blk < PBLK; blk += 16) {
    int c = cnt[blk * NCB + b];
    const unsigned* p = stg + ((size_t)blk * NCB + b) * SCAP;
    for (int e = lane; e < c; e += 64) atomicAdd(&ldeg[p[e] >> 17], 1);
  }
  __syncthreads();
  int v = ldeg[t];
  if (gid < NN) dinv[gid] = rsqrtf((float)(v + 1));  // +1 self-loop (real deg)
  int pdeg = (v + 7) & ~7;                           // pad to x8 for aggregate
  s[t] = pdeg;
  __syncthreads();
  for (int off = 1; off < 1024; off <<= 1) {
    int u = (t >= off) ? s[t - off] : 0;
    __syncthreads();
    if (t >= off) s[t] += u;
    __syncthreads();
  }
  if (gid < NN) rows[gid] = s[t] - pdeg;    // bucket-local exclusive (padded)
  if (t == 1023) part[b] = s[t];            // bucket padded total
}

__global__ void k_scan_part(const int* __restrict__ part, int* __restrict__ offs) {
  __shared__ int s[128];
  int t = threadIdx.x;
  int v = (t < NCB) ? part[t] : 0;
  s[t] = v;
  __syncthreads();
  for (int off = 1; off < 128; off <<= 1) {
    int u = (t >= off) ? s[t - off] : 0;
    __syncthreads();
    if (t >= off) s[t] += u;
    __syncthreads();
  }
  if (t < NCB) offs[t] = s[t] - v;
}

// globalize rows + fused batch-starts. rows[NN] = total padded edges.
__global__ void k_scan_add(int* __restrict__ rows, const int* __restrict__ offs,
                           const int* __restrict__ part,
                           const int* __restrict__ batch, int* __restrict__ start) {
  int i = blockIdx.x * 256 + threadIdx.x;
  if (i >= NN) return;
  rows[i] += offs[i >> 10];
  if (i == 0) rows[NN] = offs[NCB - 1] + part[NCB - 1];
  int b = batch[i];
  int prev = (i == 0) ? -1 : batch[i - 1];
  for (int g = prev + 1; g <= b; ++g) start[g] = i;
  if (i == NN - 1)
    for (int g = b + 1; g <= NG; ++g) start[g] = NN;
}

// Per bucket: place srcs via LDS cursors; fill pad slots with dummy node NN.
__global__ __launch_bounds__(1024) void k_place(const unsigned* __restrict__ stg,
                                                const int* __restrict__ cnt,
                                                const int* __restrict__ rows,
                                                int* __restrict__ csr) {
  __shared__ int lrow[1024];
  __shared__ int lcur[1024];
  int b = blockIdx.x;
  int t = threadIdx.x;
  int w = t >> 6, lane = t & 63;
  int gid = (b << CSH) + t;
  lrow[t] = (gid < NN) ? rows[gid] : 0;
  lcur[t] = 0;
  __syncthreads();
  for (int blk = w; blk < PBLK; blk += 16) {
    int c = cnt[blk * NCB + b];
    const unsigned* p = stg + ((size_t)blk * NCB + b) * SCAP;
    for (int e = lane; e < c; e += 64) {
      unsigned x = p[e];
      int ld = x >> 17;
      int q = atomicAdd(&lcur[ld], 1);
      csr[lrow[ld] + q] = (int)(x & 0x1FFFFu);
    }
  }
  __syncthreads();
  int d = lcur[t];
  int pd = (d + 7) & ~7;
  int base = lrow[t];
  for (int i = d; i < pd; ++i) csr[base + i] = NN;  // dummy zero row
}

// split W1,W2 (fp32 [k][n]) into bf16 hi/lo, transposed to [n][k]; one launch.
__global__ void k_wsplit(const float* __restrict__ W1, const float* __restrict__ W2,
                         unsigned short* __restrict__ wt1,
                         unsigned short* __restrict__ wt2) {
  int id = blockIdx.x * 256 + threadIdx.x;   // 32768
  const float* W = (id < 16384) ? W1 : W2;
  unsigned short* wt = (id < 16384) ? wt1 : wt2;
  int i = id & 16383;
  int k = i >> 7, n = i & 127;
  float w = W[i];
  unsigned short h = f2bf(w);
  unsigned short l = f2bf(w - bf2f(h));
  wt[n * 128 + k] = h;
  wt[16384 + n * 128 + k] = l;
}

// Hs(bf16) = diag(dinv) * (X @ W) via split-bf16 MFMA (XhWh + XhWl + XlWh).
__global__ __launch_bounds__(256) void k_gemm_mfma(
    const float* __restrict__ X, const unsigned short* __restrict__ wth,
    const unsigned short* __restrict__ wtl, const float* __restrict__ dinv,
    unsigned short* __restrict__ Hs) {
  __shared__ __align__(16) unsigned short sWh[64 * 136];  // [n][k] pad 136
  __shared__ __align__(16) unsigned short sWl[64 * 136];
  __shared__ __align__(16) unsigned short sXh[128 * 40];  // [row][k-chunk 32] pad 40
  __shared__ __align__(16) unsigned short sXl[128 * 40];

  const int t = threadIdx.x;
  const int w = t >> 6, lane = t & 63;
  const int quad = lane >> 4, lr = lane & 15;
  const int row0 = blockIdx.x * 128;
  const int col0 = blockIdx.y * 64;

  // zero the dummy row NN (read by k_aggregate pad slots)
  if (blockIdx.x == 0 && blockIdx.y == 0 && t < 64)
    *(unsigned*)&Hs[(size_t)NN * CH + t * 2] = 0u;

#pragma unroll
  for (int j = 0; j < 8; ++j) {
    int id = t + j * 256;
    int n = id >> 5, kk = (id & 31) * 4;
    *(ushort4*)&sWh[n * 136 + kk] = *(const ushort4*)&wth[(col0 + n) * 128 + kk];
    *(ushort4*)&sWl[n * 136 + kk] = *(const ushort4*)&wtl[(col0 + n) * 128 + kk];
  }

  float4v acc[2][4];
#pragma unroll
  for (int mi = 0; mi < 2; ++mi)
#pragma unroll
    for (int ni = 0; ni < 4; ++ni) acc[mi][ni] = (float4v){0.f, 0.f, 0.f, 0.f};

  for (int ks = 0; ks < 4; ++ks) {
    const int k0 = ks * 32;
    if (ks) __syncthreads();
#pragma unroll
    for (int i = 0; i < 4; ++i) {
      int row = i * 32 + (t >> 3);
      int seg = t & 7;
      int gr = row0 + row;
      float4 xv = {0.f, 0.f, 0.f, 0.f};
      if (gr < NN) xv = *(const float4*)&X[(size_t)gr * CH + k0 + seg * 4];
      ushort4 h, l;
      h.x = f2bf(xv.x); l.x = f2bf(xv.x - bf2f(h.x));
      h.y = f2bf(xv.y); l.y = f2bf(xv.y - bf2f(h.y));
      h.z = f2bf(xv.z); l.z = f2bf(xv.z - bf2f(h.z));
      h.w = f2bf(xv.w); l.w = f2bf(xv.w - bf2f(h.w));
      *(ushort4*)&sXh[row * 40 + seg * 4] = h;
      *(ushort4*)&sXl[row * 40 + seg * 4] = l;
    }
    __syncthreads();

    short8v ah[2], al[2];
#pragma unroll
    for (int mi = 0; mi < 2; ++mi) {
      int r = w * 32 + mi * 16 + lr;
      ah[mi] = *(const short8v*)&sXh[r * 40 + quad * 8];
      al[mi] = *(const short8v*)&sXl[r * 40 + quad * 8];
    }
#pragma unroll
    for (int ni = 0; ni < 4; ++ni) {
      int n = ni * 16 + lr;
      short8v bh = *(const short8v*)&sWh[n * 136 + k0 + quad * 8];
      short8v bl = *(const short8v*)&sWl[n * 136 + k0 + quad * 8];
#pragma unroll
      for (int mi = 0; mi < 2; ++mi) {
        acc[mi][ni] = __builtin_amdgcn_mfma_f32_16x16x32_bf16(ah[mi], bh, acc[mi][ni], 0, 0, 0);
        acc[mi][ni] = __builtin_amdgcn_mfma_f32_16x16x32_bf16(ah[mi], bl, acc[mi][ni], 0, 0, 0);
        acc[mi][ni] = __builtin_amdgcn_mfma_f32_16x16x32_bf16(al[mi], bh, acc[mi][ni], 0, 0, 0);
      }
    }
  }

#pragma unroll
  for (int mi = 0; mi < 2; ++mi) {
#pragma unroll
    for (int r = 0; r < 4; ++r) {
      int grow = row0 + w * 32 + mi * 16 + quad * 4 + r;
      if (grow < NN) {
        float d = dinv[grow];
#pragma unroll
        for (int ni = 0; ni < 4; ++ni)
          Hs[(size_t)grow * CH + col0 + ni * 16 + lr] = f2bf(d * acc[mi][ni][r]);
      }
    }
  }
}

// out[i] = relu(dinv[i]*(Hs[i] + sum Hs[csr[e]]) + b). One wave per node.
// Two rows per gather instruction: half-wave 0 reads even edges, half-wave 1
// odd edges, each lane 8B (4 channels). Cross-half shfl_xor merge at end.
// Halves wave-level VMEM gather instructions vs one-row-per-inst.
__global__ __launch_bounds__(256) void k_aggregate(
    const uint2* __restrict__ H2, const int* __restrict__ rows,
    const int* __restrict__ csr, const float* __restrict__ dinv,
    const float* __restrict__ bias, float* __restrict__ out) {
  int node = blockIdx.x * 4 + (threadIdx.x >> 6);
  int lane = threadIdx.x & 63;
  int half = lane >> 5;
  int l32 = lane & 31;   // uint2 index within row -> channels 4*l32..4*l32+3
  if (node >= NN) return;
  float c0 = 0.f, c1 = 0.f, c2 = 0.f, c3 = 0.f;
  int e0 = rows[node], e1 = rows[node + 1];  // padded to x8
  if (e1 > e0) {
    uint2 va[4], vb[4];
    int jn[8];
#pragma unroll
    for (int k = 0; k < 8; ++k) jn[k] = csr[e0 + k];
#pragma unroll
    for (int k = 0; k < 4; ++k) {
      int j = half ? jn[2 * k + 1] : jn[2 * k];
      va[k] = H2[((unsigned)j << 5) | l32];
    }
    for (int base = e0 + 8; base < e1; base += 8) {
#pragma unroll
      for (int k = 0; k < 8; ++k) jn[k] = csr[base + k];
#pragma unroll
      for (int k = 0; k < 4; ++k) {
        int j = half ? jn[2 * k + 1] : jn[2 * k];
        vb[k] = H2[((unsigned)j << 5) | l32];
      }
#pragma unroll
      for (int k = 0; k < 4; ++k) {
        c0 += bflo(va[k].x); c1 += bfhi(va[k].x);
        c2 += bflo(va[k].y); c3 += bfhi(va[k].y);
      }
#pragma unroll
      for (int k = 0; k < 4; ++k) va[k] = vb[k];
    }
#pragma unroll
    for (int k = 0; k < 4; ++k) {
      c0 += bflo(va[k].x); c1 += bfhi(va[k].x);
      c2 += bflo(va[k].y); c3 += bfhi(va[k].y);
    }
  }
  // merge the two half-wave partial sums (same channels, different edges)
  c0 += __shfl_xor(c0, 32, 64);
  c1 += __shfl_xor(c1, 32, 64);
  c2 += __shfl_xor(c2, 32, 64);
  c3 += __shfl_xor(c3, 32, 64);
  // self-loop row (both halves load same 2 lines; L1-hot)
  uint2 sv = H2[((unsigned)node << 5) | l32];
  c0 += bflo(sv.x); c1 += bfhi(sv.x);
  c2 += bflo(sv.y); c3 += bfhi(sv.y);
  if (half == 0) {
    float d = dinv[node];
    float4 bv = *(const float4*)&bias[4 * l32];
    float4 o;
    o.x = fmaxf(fmaf(d, c0, bv.x), 0.f);
    o.y = fmaxf(fmaf(d, c1, bv.y), 0.f);
    o.z = fmaxf(fmaf(d, c2, bv.z), 0.f);
    o.w = fmaxf(fmaf(d, c3, bv.w), 0.f);
    *(float4*)&out[(size_t)node * CH + 4 * l32] = o;
  }
}

// Fused per-graph pipeline: segmented mean pool -> MLP1 (relu) -> MLP2 -> out.
__global__ __launch_bounds__(256) void k_head(
    const float* __restrict__ A, const int* __restrict__ start,
    const float* __restrict__ W3, const float* __restrict__ b3,
    const float* __restrict__ W4, const float* __restrict__ b4,
    float* __restrict__ out) {
  __shared__ float pooled[128];
  __shared__ float part[128];
  __shared__ float g1[128];
  int g = blockIdx.x;
  int c = threadIdx.x & 127;
  int half = threadIdx.x >> 7;
  int s0 = start[g], s1 = start[g + 1];
  float sum = 0.f;
  for (int i = s0 + half; i < s1; i += 2)
    sum += A[(size_t)i * CH + c];
  if (half) part[c] = sum;
  __syncthreads();
  if (!half) {
    float n = fmaxf((float)(s1 - s0), 1.0f);
    pooled[c] = (sum + part[c]) / n;
  }
  __syncthreads();
  if (threadIdx.x < 128) {
    float acc = b3[c];
    for (int k = 0; k < 128; ++k) acc += pooled[k] * W3[k * CH + c];
    g1[c] = fmaxf(acc, 0.f);
  }
  __syncthreads();
  if (threadIdx.x < 64) {
    float acc = b4[threadIdx.x];
    for (int k = 0; k < 128; ++k) acc += g1[k] * W4[k * OC + threadIdx.x];
    out[(size_t)g * OC + threadIdx.x] = acc;
  }
}

extern "C" void kernel_launch(void* const* d_in, const int* in_sizes, int n_in,
                              void* d_out, int out_size, void* d_ws, size_t ws_size,
                              hipStream_t stream) {
  const float* X   = (const float*)d_in[0];
  const int* ei    = (const int*)d_in[1];
  const int* batch = (const int*)d_in[2];
  const float* W1  = (const float*)d_in[3];
  const float* b1  = (const float*)d_in[4];
  const float* W2  = (const float*)d_in[5];
  const float* b2  = (const float*)d_in[6];
  const float* W3  = (const float*)d_in[7];
  const float* b3  = (const float*)d_in[8];
  const float* W4  = (const float*)d_in[9];
  const float* b4  = (const float*)d_in[10];
  float* out = (float*)d_out;
  float* ws = (float*)d_ws;

  const int* src = ei;        // edge_index[0]
  const int* dst = ei + EE;   // edge_index[1]

  float* dinv = ws + O_DINV;
  int* rows   = (int*)(ws + O_ROWS);
  int* cnt    = (int*)(ws + O_CNT);
  int* part   = (int*)(ws + O_PART);
  int* offs   = (int*)(ws + O_OFFS);
  int* start  = (int*)(ws + O_START);
  int* csr    = (int*)(ws + O_CSR);
  unsigned short* Hs = (unsigned short*)(ws + O_HS);
  unsigned* stg = (unsigned*)(ws + O_STG);
  unsigned short* wt1 = (unsigned short*)(ws + O_WT1);
  unsigned short* wt2 = (unsigned short*)(ws + O_WT2);
  float* A1   = ws + O_A1;

  k_part<<<PBLK, 1024, 0, stream>>>(src, dst, cnt, stg);
  k_count<<<NCB, 1024, 0, stream>>>(stg, cnt, rows, part, dinv);
  k_scan_part<<<1, 128, 0, stream>>>(part, offs);
  k_scan_add<<<(NN + 255) / 256, 256, 0, stream>>>(rows, offs, part, batch, start);
  k_place<<<NCB, 1024, 0, stream>>>(stg, cnt, rows, csr);
  // after k_place the staging region is dead; wt1/wt2 overwrite its start
  k_wsplit<<<128, 256, 0, stream>>>(W1, W2, wt1, wt2);

  dim3 ggrid((NN + 127) / 128, 2);
  // layer 1
  k_gemm_mfma<<<ggrid, 256, 0, stream>>>(X, wt1, wt1 + 16384, dinv, Hs);
  k_aggregate<<<(NN + 3) / 4, 256, 0, stream>>>((const uint2*)Hs, rows, csr, dinv, b1, A1);
  // layer 2
  k_gemm_mfma<<<ggrid, 256, 0, stream>>>(A1, wt2, wt2 + 16384, dinv, Hs);
  k_aggregate<<<(NN + 3) / 4, 256, 0, stream>>>((const uint2*)Hs, rows, csr, dinv, b2, A1);

  k_head<<<NG, 256, 0, stream>>>(A1, start, W3, b3, W4, b4, out);
}

// Round 14
// 405.663 us; speedup vs baseline: 1.0601x; 1.0601x over previous
//
#include <hip/hip_runtime.h>

#define NN 100000
#define EE 1600000
#define CH 128
#define NG 512
#define OC 64

// coarse radix partition: 98 buckets of 1024 nodes; fixed-capacity staging cells
#define CSH 10
#define NCB 98
#define PBLK 256
#define PCHUNK 6250     // 256*6250 = 1.6M exactly
#define SCAP 128        // per (block,bucket) cell: mean 63.8 + 8 sigma

// workspace element offsets (4-byte units); total 110.4 MB
#define O_DINV   0
#define O_ROWS   100032   // 100001
#define O_CNT    200064   // 25088
#define O_PART   225152
#define O_OFFS   225280
#define O_START  225408   // 513
#define O_CSR    225984   // padded CSR, cap 2.50M words (sum pdeg <= 2.3M)
#define O_HS     2726016  // bf16 Hs: (NN+1) rows x 128 ushorts = 6400064 words
#define O_STG    9126080  // staging 3.21M words (dead after k_place)
#define O_WT1    9126080  // split W1: 32768 ushorts = 16384 words
#define O_WT2    9142464
#define O_A1     14800448 // fp32 A1: 12.8M words

typedef __attribute__((ext_vector_type(8))) short short8v;
typedef __attribute__((ext_vector_type(4))) float float4v;

static __device__ __forceinline__ unsigned short f2bf(float x) {
  unsigned u = __float_as_uint(x);
  return (unsigned short)((u + 0x7FFFu + ((u >> 16) & 1u)) >> 16);  // RNE
}
static __device__ __forceinline__ float bf2f(unsigned short h) {
  return __uint_as_float((unsigned)h << 16);
}
static __device__ __forceinline__ float bflo(unsigned v) {
  return __uint_as_float(v << 16);
}
static __device__ __forceinline__ float bfhi(unsigned v) {
  return __uint_as_float(v & 0xFFFF0000u);
}

// LDS radix scatter: hist -> scan -> ordered LDS buffer -> contiguous run copies.
__global__ __launch_bounds__(1024) void k_part(const int* __restrict__ src,
                                               const int* __restrict__ dst,
                                               int* __restrict__ cnt,
                                               unsigned* __restrict__ stg) {
  __shared__ int hist[NCB];   // counts, then exclusive bases
  __shared__ int lcur[NCB];
  __shared__ unsigned lout[PCHUNK];
  int t = threadIdx.x;
  int e0 = blockIdx.x * PCHUNK;
  if (t < NCB) { hist[t] = 0; lcur[t] = 0; }
  __syncthreads();
  for (int e = e0 + t; e < e0 + PCHUNK; e += 1024)
    atomicAdd(&hist[dst[e] >> CSH], 1);
  __syncthreads();
  if (t == 0) {
    int s = 0;
    for (int i = 0; i < NCB; ++i) { int v = hist[i]; hist[i] = s; s += v; }
  }
  __syncthreads();
  for (int e = e0 + t; e < e0 + PCHUNK; e += 1024) {
    int d = dst[e];
    int b = d >> CSH;
    int p = hist[b] + atomicAdd(&lcur[b], 1);
    lout[p] = (unsigned)src[e] | ((unsigned)(d & 1023) << 17);
  }
  __syncthreads();
  int w = t >> 6, lane = t & 63;
  unsigned* mystg = stg + (size_t)blockIdx.x * NCB * SCAP;
  for (int b = w; b < NCB; b += 16) {
    int beg = hist[b];
    int end = (b == NCB - 1) ? PCHUNK : hist[b + 1];
    int n = min(end - beg, SCAP);
    for (int i = lane; i < n; i += 64) mystg[b * SCAP + i] = lout[beg + i];
    if (lane == 0) cnt[blockIdx.x * NCB + b] = n;
  }
}

// Per bucket: degree histogram, dinv (real deg), exclusive scan of PADDED deg.
__global__ __launch_bounds__(1024) void k_count(const unsigned* __restrict__ stg,
                                                const int* __restrict__ cnt,
                                                int* __restrict__ rows,
                                                int* __restrict__ part,
                                                float* __restrict__ dinv) {
  __shared__ int ldeg[1024];
  __shared__ int s[1024];
  int b = blockIdx.x;
  int t = threadIdx.x;
  int w = t >> 6, lane = t & 63;
  int gid = (b << CSH) + t;
  ldeg[t] = 0;
  __syncthreads();
  for (int blk = w; blk < PBLK; blk += 16) {
    int c = cnt[blk * NCB + b];
    const unsigned* p = stg + ((size_t)blk * NCB + b) * SCAP;
    for (int e = lane; e < c; e += 64) atomicAdd(&ldeg[p[e] >> 17], 1);
  }
  __syncthreads();
  int v = ldeg[t];
  if (gid < NN) dinv[gid] = rsqrtf((float)(v + 1));  // +1 self-loop (real deg)
  int pdeg = (v + 7) & ~7;                           // pad to x8 for aggregate
  s[t] = pdeg;
  __syncthreads();
  for (int off = 1; off < 1024; off <<= 1) {
    int u = (t >= off) ? s[t - off] : 0;
    __syncthreads();
    if (t >= off) s[t] += u;
    __syncthreads();
  }
  if (gid < NN) rows[gid] = s[t] - pdeg;    // bucket-local exclusive (padded)
  if (t == 1023) part[b] = s[t];            // bucket padded total
}

__global__ void k_scan_part(const int* __restrict__ part, int* __restrict__ offs) {
  __shared__ int s[128];
  int t = threadIdx.x;
  int v = (t < NCB) ? part[t] : 0;
  s[t] = v;
  __syncthreads();
  for (int off = 1; off < 128; off <<= 1) {
    int u = (t >= off) ? s[t - off] : 0;
    __syncthreads();
    if (t >= off) s[t] += u;
    __syncthreads();
  }
  if (t < NCB) offs[t] = s[t] - v;
}

// globalize rows + fused batch-starts. rows[NN] = total padded edges.
__global__ void k_scan_add(int* __restrict__ rows, const int* __restrict__ offs,
                           const int* __restrict__ part,
                           const int* __restrict__ batch, int* __restrict__ start) {
  int i = blockIdx.x * 256 + threadIdx.x;
  if (i >= NN) return;
  rows[i] += offs[i >> 10];
  if (i == 0) rows[NN] = offs[NCB - 1] + part[NCB - 1];
  int b = batch[i];
  int prev = (i == 0) ? -1 : batch[i - 1];
  for (int g = prev + 1; g <= b; ++g) start[g] = i;
  if (i == NN - 1)
    for (int g = b + 1; g <= NG; ++g) start[g] = NN;
}

// Per bucket: place srcs via LDS cursors; fill pad slots with dummy node NN.
__global__ __launch_bounds__(1024) void k_place(const unsigned* __restrict__ stg,
                                                const int* __restrict__ cnt,
                                                const int* __restrict__ rows,
                                                int* __restrict__ csr) {
  __shared__ int lrow[1024];
  __shared__ int lcur[1024];
  int b = blockIdx.x;
  int t = threadIdx.x;
  int w = t >> 6, lane = t & 63;
  int gid = (b << CSH) + t;
  lrow[t] = (gid < NN) ? rows[gid] : 0;
  lcur[t] = 0;
  __syncthreads();
  for (int blk = w; blk < PBLK; blk += 16) {
    int c = cnt[blk * NCB + b];
    const unsigned* p = stg + ((size_t)blk * NCB + b) * SCAP;
    for (int e = lane; e < c; e += 64) {
      unsigned x = p[e];
      int ld = x >> 17;
      int q = atomicAdd(&lcur[ld], 1);
      csr[lrow[ld] + q] = (int)(x & 0x1FFFFu);
    }
  }
  __syncthreads();
  int d = lcur[t];
  int pd = (d + 7) & ~7;
  int base = lrow[t];
  for (int i = d; i < pd; ++i) csr[base + i] = NN;  // dummy zero row
}

// split W1,W2 (fp32 [k][n]) into bf16 hi/lo, transposed to [n][k]; one launch.
__global__ void k_wsplit(const float* __restrict__ W1, const float* __restrict__ W2,
                         unsigned short* __restrict__ wt1,
                         unsigned short* __restrict__ wt2) {
  int id = blockIdx.x * 256 + threadIdx.x;   // 32768
  const float* W = (id < 16384) ? W1 : W2;
  unsigned short* wt = (id < 16384) ? wt1 : wt2;
  int i = id & 16383;
  int k = i >> 7, n = i & 127;
  float w = W[i];
  unsigned short h = f2bf(w);
  unsigned short l = f2bf(w - bf2f(h));
  wt[n * 128 + k] = h;
  wt[16384 + n * 128 + k] = l;
}

// Hs(bf16) = diag(dinv) * (X @ W) via split-bf16 MFMA (XhWh + XhWl + XlWh).
__global__ __launch_bounds__(256) void k_gemm_mfma(
    const float* __restrict__ X, const unsigned short* __restrict__ wth,
    const unsigned short* __restrict__ wtl, const float* __restrict__ dinv,
    unsigned short* __restrict__ Hs) {
  __shared__ __align__(16) unsigned short sWh[64 * 136];  // [n][k] pad 136
  __shared__ __align__(16) unsigned short sWl[64 * 136];
  __shared__ __align__(16) unsigned short sXh[128 * 40];  // [row][k-chunk 32] pad 40
  __shared__ __align__(16) unsigned short sXl[128 * 40];

  const int t = threadIdx.x;
  const int w = t >> 6, lane = t & 63;
  const int quad = lane >> 4, lr = lane & 15;
  const int row0 = blockIdx.x * 128;
  const int col0 = blockIdx.y * 64;

  // zero the dummy row NN (read by k_aggregate pad slots)
  if (blockIdx.x == 0 && blockIdx.y == 0 && t < 64)
    *(unsigned*)&Hs[(size_t)NN * CH + t * 2] = 0u;

#pragma unroll
  for (int j = 0; j < 8; ++j) {
    int id = t + j * 256;
    int n = id >> 5, kk = (id & 31) * 4;
    *(ushort4*)&sWh[n * 136 + kk] = *(const ushort4*)&wth[(col0 + n) * 128 + kk];
    *(ushort4*)&sWl[n * 136 + kk] = *(const ushort4*)&wtl[(col0 + n) * 128 + kk];
  }

  float4v acc[2][4];
#pragma unroll
  for (int mi = 0; mi < 2; ++mi)
#pragma unroll
    for (int ni = 0; ni < 4; ++ni) acc[mi][ni] = (float4v){0.f, 0.f, 0.f, 0.f};

  for (int ks = 0; ks < 4; ++ks) {
    const int k0 = ks * 32;
    if (ks) __syncthreads();
#pragma unroll
    for (int i = 0; i < 4; ++i) {
      int row = i * 32 + (t >> 3);
      int seg = t & 7;
      int gr = row0 + row;
      float4 xv = {0.f, 0.f, 0.f, 0.f};
      if (gr < NN) xv = *(const float4*)&X[(size_t)gr * CH + k0 + seg * 4];
      ushort4 h, l;
      h.x = f2bf(xv.x); l.x = f2bf(xv.x - bf2f(h.x));
      h.y = f2bf(xv.y); l.y = f2bf(xv.y - bf2f(h.y));
      h.z = f2bf(xv.z); l.z = f2bf(xv.z - bf2f(h.z));
      h.w = f2bf(xv.w); l.w = f2bf(xv.w - bf2f(h.w));
      *(ushort4*)&sXh[row * 40 + seg * 4] = h;
      *(ushort4*)&sXl[row * 40 + seg * 4] = l;
    }
    __syncthreads();

    short8v ah[2], al[2];
#pragma unroll
    for (int mi = 0; mi < 2; ++mi) {
      int r = w * 32 + mi * 16 + lr;
      ah[mi] = *(const short8v*)&sXh[r * 40 + quad * 8];
      al[mi] = *(const short8v*)&sXl[r * 40 + quad * 8];
    }
#pragma unroll
    for (int ni = 0; ni < 4; ++ni) {
      int n = ni * 16 + lr;
      short8v bh = *(const short8v*)&sWh[n * 136 + k0 + quad * 8];
      short8v bl = *(const short8v*)&sWl[n * 136 + k0 + quad * 8];
#pragma unroll
      for (int mi = 0; mi < 2; ++mi) {
        acc[mi][ni] = __builtin_amdgcn_mfma_f32_16x16x32_bf16(ah[mi], bh, acc[mi][ni], 0, 0, 0);
        acc[mi][ni] = __builtin_amdgcn_mfma_f32_16x16x32_bf16(ah[mi], bl, acc[mi][ni], 0, 0, 0);
        acc[mi][ni] = __builtin_amdgcn_mfma_f32_16x16x32_bf16(al[mi], bh, acc[mi][ni], 0, 0, 0);
      }
    }
  }

#pragma unroll
  for (int mi = 0; mi < 2; ++mi) {
#pragma unroll
    for (int r = 0; r < 4; ++r) {
      int grow = row0 + w * 32 + mi * 16 + quad * 4 + r;
      if (grow < NN) {
        float d = dinv[grow];
#pragma unroll
        for (int ni = 0; ni < 4; ++ni)
          Hs[(size_t)grow * CH + col0 + ni * 16 + lr] = f2bf(d * acc[mi][ni][r]);
      }
    }
  }
}

// out[i] = relu(dinv[i]*(Hs[i] + sum Hs[csr[e]]) + b). One wave per node.
// CSR padded to x8 with dummy zero-row indices: uniform exact 8-groups,
// no clamp/tail masking; 32-bit offsets; 16 gathers in flight. (r12 form —
// verified local optimum; half-wave dwordx2 + shfl merge regressed, r13.)
__global__ __launch_bounds__(256) void k_aggregate(
    const unsigned* __restrict__ H, const int* __restrict__ rows,
    const int* __restrict__ csr, const float* __restrict__ dinv,
    const float* __restrict__ bias, float* __restrict__ out) {
  int node = blockIdx.x * 4 + (threadIdx.x >> 6);
  int lane = threadIdx.x & 63;
  if (node >= NN) return;
  float bx = bias[2 * lane], by = bias[2 * lane + 1];
  unsigned sv = H[((unsigned)node << 6) | lane];  // self-loop term
  float ax = bflo(sv), ay = bfhi(sv);
  int e0 = rows[node], e1 = rows[node + 1];  // padded, multiple of 8
  if (e1 > e0) {
    unsigned va[8], vb[8];
#pragma unroll
    for (int k = 0; k < 8; ++k)
      va[k] = H[((unsigned)csr[e0 + k] << 6) | lane];
    for (int base = e0 + 8; base < e1; base += 8) {
#pragma unroll
      for (int k = 0; k < 8; ++k)
        vb[k] = H[((unsigned)csr[base + k] << 6) | lane];
#pragma unroll
      for (int k = 0; k < 8; ++k) { ax += bflo(va[k]); ay += bfhi(va[k]); }
#pragma unroll
      for (int k = 0; k < 8; ++k) va[k] = vb[k];
    }
#pragma unroll
    for (int k = 0; k < 8; ++k) { ax += bflo(va[k]); ay += bfhi(va[k]); }
  }
  float d = dinv[node];
  float2 o;
  o.x = fmaxf(fmaf(d, ax, bx), 0.f);
  o.y = fmaxf(fmaf(d, ay, by), 0.f);
  ((float2*)out)[(size_t)node * 64 + lane] = o;
}

// Fused per-graph pipeline: segmented mean pool -> MLP1 (relu) -> MLP2 -> out.
__global__ __launch_bounds__(256) void k_head(
    const float* __restrict__ A, const int* __restrict__ start,
    const float* __restrict__ W3, const float* __restrict__ b3,
    const float* __restrict__ W4, const float* __restrict__ b4,
    float* __restrict__ out) {
  __shared__ float pooled[128];
  __shared__ float part[128];
  __shared__ float g1[128];
  int g = blockIdx.x;
  int c = threadIdx.x & 127;
  int half = threadIdx.x >> 7;
  int s0 = start[g], s1 = start[g + 1];
  float sum = 0.f;
  for (int i = s0 + half; i < s1; i += 2)
    sum += A[(size_t)i * CH + c];
  if (half) part[c] = sum;
  __syncthreads();
  if (!half) {
    float n = fmaxf((float)(s1 - s0), 1.0f);
    pooled[c] = (sum + part[c]) / n;
  }
  __syncthreads();
  if (threadIdx.x < 128) {
    float acc = b3[c];
    for (int k = 0; k < 128; ++k) acc += pooled[k] * W3[k * CH + c];
    g1[c] = fmaxf(acc, 0.f);
  }
  __syncthreads();
  if (threadIdx.x < 64) {
    float acc = b4[threadIdx.x];
    for (int k = 0; k < 128; ++k) acc += g1[k] * W4[k * OC + threadIdx.x];
    out[(size_t)g * OC + threadIdx.x] = acc;
  }
}

extern "C" void kernel_launch(void* const* d_in, const int* in_sizes, int n_in,
                              void* d_out, int out_size, void* d_ws, size_t ws_size,
                              hipStream_t stream) {
  const float* X   = (const float*)d_in[0];
  const int* ei    = (const int*)d_in[1];
  const int* batch = (const int*)d_in[2];
  const float* W1  = (const float*)d_in[3];
  const float* b1  = (const float*)d_in[4];
  const float* W2  = (const float*)d_in[5];
  const float* b2  = (const float*)d_in[6];
  const float* W3  = (const float*)d_in[7];
  const float* b3  = (const float*)d_in[8];
  const float* W4  = (const float*)d_in[9];
  const float* b4  = (const float*)d_in[10];
  float* out = (float*)d_out;
  float* ws = (float*)d_ws;

  const int* src = ei;        // edge_index[0]
  const int* dst = ei + EE;   // edge_index[1]

  float* dinv = ws + O_DINV;
  int* rows   = (int*)(ws + O_ROWS);
  int* cnt    = (int*)(ws + O_CNT);
  int* part   = (int*)(ws + O_PART);
  int* offs   = (int*)(ws + O_OFFS);
  int* start  = (int*)(ws + O_START);
  int* csr    = (int*)(ws + O_CSR);
  unsigned short* Hs = (unsigned short*)(ws + O_HS);
  unsigned* stg = (unsigned*)(ws + O_STG);
  unsigned short* wt1 = (unsigned short*)(ws + O_WT1);
  unsigned short* wt2 = (unsigned short*)(ws + O_WT2);
  float* A1   = ws + O_A1;

  k_part<<<PBLK, 1024, 0, stream>>>(src, dst, cnt, stg);
  k_count<<<NCB, 1024, 0, stream>>>(stg, cnt, rows, part, dinv);
  k_scan_part<<<1, 128, 0, stream>>>(part, offs);
  k_scan_add<<<(NN + 255) / 256, 256, 0, stream>>>(rows, offs, part, batch, start);
  k_place<<<NCB, 1024, 0, stream>>>(stg, cnt, rows, csr);
  // after k_place the staging region is dead; wt1/wt2 overwrite its start
  k_wsplit<<<128, 256, 0, stream>>>(W1, W2, wt1, wt2);

  dim3 ggrid((NN + 127) / 128, 2);
  // layer 1
  k_gemm_mfma<<<ggrid, 256, 0, stream>>>(X, wt1, wt1 + 16384, dinv, Hs);
  k_aggregate<<<(NN + 3) / 4, 256, 0, stream>>>((const unsigned*)Hs, rows, csr, dinv, b1, A1);
  // layer 2
  k_gemm_mfma<<<ggrid, 256, 0, stream>>>(A1, wt2, wt2 + 16384, dinv, Hs);
  k_aggregate<<<(NN + 3) / 4, 256, 0, stream>>>((const unsigned*)Hs, rows, csr, dinv, b2, A1);

  k_head<<<NG, 256, 0, stream>>>(A1, start, W3, b3, W4, b4, out);
}

// Round 15
// 378.009 us; speedup vs baseline: 1.1377x; 1.0732x over previous
//
#include <hip/hip_runtime.h>

#define NN 100000
#define EE 1600000
#define CH 128
#define NG 512
#define OC 64

// coarse radix partition: 98 buckets of 1024 nodes; fixed-capacity staging cells
#define CSH 10
#define NCB 98
#define PBLK 256
#define PCHUNK 6250     // 256*6250 = 1.6M exactly
#define SCAP 128        // per (block,bucket) cell: mean 63.8 + 8 sigma

// workspace element offsets (4-byte units); total 110.4 MB
#define O_DINV   0
#define O_ROWS   100032   // 100001
#define O_CNT    200064   // 25088
#define O_PART   225152
#define O_OFFS   225280
#define O_START  225408   // 513
#define O_CSR    225984   // padded CSR, cap 2.50M words (sum pdeg <= 2.3M)
#define O_HS     2726016  // bf16 Hs: (NN+1) rows x 128 ushorts = 6400064 words
#define O_STG    9126080  // staging 3.21M words (dead after k_place)
#define O_WT1    9126080  // split W1: 32768 ushorts = 16384 words
#define O_WT2    9142464
#define O_A1     14800448 // bf16 A1: NN x 128 ushorts = 6.4M words

typedef __attribute__((ext_vector_type(8))) short short8v;
typedef __attribute__((ext_vector_type(4))) float float4v;

static __device__ __forceinline__ unsigned short f2bf(float x) {
  unsigned u = __float_as_uint(x);
  return (unsigned short)((u + 0x7FFFu + ((u >> 16) & 1u)) >> 16);  // RNE
}
static __device__ __forceinline__ float bf2f(unsigned short h) {
  return __uint_as_float((unsigned)h << 16);
}
static __device__ __forceinline__ unsigned pack2(float a, float b) {
  return (unsigned)f2bf(a) | ((unsigned)f2bf(b) << 16);
}
static __device__ __forceinline__ float bflo(unsigned v) {
  return __uint_as_float(v << 16);
}
static __device__ __forceinline__ float bfhi(unsigned v) {
  return __uint_as_float(v & 0xFFFF0000u);
}

// LDS radix scatter: hist -> scan -> ordered LDS buffer -> contiguous run copies.
__global__ __launch_bounds__(1024) void k_part(const int* __restrict__ src,
                                               const int* __restrict__ dst,
                                               int* __restrict__ cnt,
                                               unsigned* __restrict__ stg) {
  __shared__ int hist[NCB];   // counts, then exclusive bases
  __shared__ int lcur[NCB];
  __shared__ unsigned lout[PCHUNK];
  int t = threadIdx.x;
  int e0 = blockIdx.x * PCHUNK;
  if (t < NCB) { hist[t] = 0; lcur[t] = 0; }
  __syncthreads();
  for (int e = e0 + t; e < e0 + PCHUNK; e += 1024)
    atomicAdd(&hist[dst[e] >> CSH], 1);
  __syncthreads();
  if (t == 0) {
    int s = 0;
    for (int i = 0; i < NCB; ++i) { int v = hist[i]; hist[i] = s; s += v; }
  }
  __syncthreads();
  for (int e = e0 + t; e < e0 + PCHUNK; e += 1024) {
    int d = dst[e];
    int b = d >> CSH;
    int p = hist[b] + atomicAdd(&lcur[b], 1);
    lout[p] = (unsigned)src[e] | ((unsigned)(d & 1023) << 17);
  }
  __syncthreads();
  int w = t >> 6, lane = t & 63;
  unsigned* mystg = stg + (size_t)blockIdx.x * NCB * SCAP;
  for (int b = w; b < NCB; b += 16) {
    int beg = hist[b];
    int end = (b == NCB - 1) ? PCHUNK : hist[b + 1];
    int n = min(end - beg, SCAP);
    for (int i = lane; i < n; i += 64) mystg[b * SCAP + i] = lout[beg + i];
    if (lane == 0) cnt[blockIdx.x * NCB + b] = n;
  }
}

// Per bucket: degree histogram, dinv (real deg), exclusive scan of PADDED deg.
__global__ __launch_bounds__(1024) void k_count(const unsigned* __restrict__ stg,
                                                const int* __restrict__ cnt,
                                                int* __restrict__ rows,
                                                int* __restrict__ part,
                                                float* __restrict__ dinv) {
  __shared__ int ldeg[1024];
  __shared__ int s[1024];
  int b = blockIdx.x;
  int t = threadIdx.x;
  int w = t >> 6, lane = t & 63;
  int gid = (b << CSH) + t;
  ldeg[t] = 0;
  __syncthreads();
  for (int blk = w; blk < PBLK; blk += 16) {
    int c = cnt[blk * NCB + b];
    const unsigned* p = stg + ((size_t)blk * NCB + b) * SCAP;
    for (int e = lane; e < c; e += 64) atomicAdd(&ldeg[p[e] >> 17], 1);
  }
  __syncthreads();
  int v = ldeg[t];
  if (gid < NN) dinv[gid] = rsqrtf((float)(v + 1));  // +1 self-loop (real deg)
  int pdeg = (v + 7) & ~7;                           // pad to x8 for aggregate
  s[t] = pdeg;
  __syncthreads();
  for (int off = 1; off < 1024; off <<= 1) {
    int u = (t >= off) ? s[t - off] : 0;
    __syncthreads();
    if (t >= off) s[t] += u;
    __syncthreads();
  }
  if (gid < NN) rows[gid] = s[t] - pdeg;    // bucket-local exclusive (padded)
  if (t == 1023) part[b] = s[t];            // bucket padded total
}

__global__ void k_scan_part(const int* __restrict__ part, int* __restrict__ offs) {
  __shared__ int s[128];
  int t = threadIdx.x;
  int v = (t < NCB) ? part[t] : 0;
  s[t] = v;
  __syncthreads();
  for (int off = 1; off < 128; off <<= 1) {
    int u = (t >= off) ? s[t - off] : 0;
    __syncthreads();
    if (t >= off) s[t] += u;
    __syncthreads();
  }
  if (t < NCB) offs[t] = s[t] - v;
}

// globalize rows + fused batch-starts. rows[NN] = total padded edges.
__global__ void k_scan_add(int* __restrict__ rows, const int* __restrict__ offs,
                           const int* __restrict__ part,
                           const int* __restrict__ batch, int* __restrict__ start) {
  int i = blockIdx.x * 256 + threadIdx.x;
  if (i >= NN) return;
  rows[i] += offs[i >> 10];
  if (i == 0) rows[NN] = offs[NCB - 1] + part[NCB - 1];
  int b = batch[i];
  int prev = (i == 0) ? -1 : batch[i - 1];
  for (int g = prev + 1; g <= b; ++g) start[g] = i;
  if (i == NN - 1)
    for (int g = b + 1; g <= NG; ++g) start[g] = NN;
}

// Per bucket: place srcs via LDS cursors; fill pad slots with dummy node NN.
__global__ __launch_bounds__(1024) void k_place(const unsigned* __restrict__ stg,
                                                const int* __restrict__ cnt,
                                                const int* __restrict__ rows,
                                                int* __restrict__ csr) {
  __shared__ int lrow[1024];
  __shared__ int lcur[1024];
  int b = blockIdx.x;
  int t = threadIdx.x;
  int w = t >> 6, lane = t & 63;
  int gid = (b << CSH) + t;
  lrow[t] = (gid < NN) ? rows[gid] : 0;
  lcur[t] = 0;
  __syncthreads();
  for (int blk = w; blk < PBLK; blk += 16) {
    int c = cnt[blk * NCB + b];
    const unsigned* p = stg + ((size_t)blk * NCB + b) * SCAP;
    for (int e = lane; e < c; e += 64) {
      unsigned x = p[e];
      int ld = x >> 17;
      int q = atomicAdd(&lcur[ld], 1);
      csr[lrow[ld] + q] = (int)(x & 0x1FFFFu);
    }
  }
  __syncthreads();
  int d = lcur[t];
  int pd = (d + 7) & ~7;
  int base = lrow[t];
  for (int i = d; i < pd; ++i) csr[base + i] = NN;  // dummy zero row
}

// split W1,W2 (fp32 [k][n]) into bf16 hi/lo, transposed to [n][k]; one launch.
__global__ void k_wsplit(const float* __restrict__ W1, const float* __restrict__ W2,
                         unsigned short* __restrict__ wt1,
                         unsigned short* __restrict__ wt2) {
  int id = blockIdx.x * 256 + threadIdx.x;   // 32768
  const float* W = (id < 16384) ? W1 : W2;
  unsigned short* wt = (id < 16384) ? wt1 : wt2;
  int i = id & 16383;
  int k = i >> 7, n = i & 127;
  float w = W[i];
  unsigned short h = f2bf(w);
  unsigned short l = f2bf(w - bf2f(h));
  wt[n * 128 + k] = h;
  wt[16384 + n * 128 + k] = l;
}

// Layer-1: Hs(bf16) = diag(dinv) * (X_fp32 @ W) via split-bf16 MFMA (3 terms).
__global__ __launch_bounds__(256) void k_gemm_mfma(
    const float* __restrict__ X, const unsigned short* __restrict__ wth,
    const unsigned short* __restrict__ wtl, const float* __restrict__ dinv,
    unsigned short* __restrict__ Hs) {
  __shared__ __align__(16) unsigned short sWh[64 * 136];  // [n][k] pad 136
  __shared__ __align__(16) unsigned short sWl[64 * 136];
  __shared__ __align__(16) unsigned short sXh[128 * 40];  // [row][k-chunk 32] pad 40
  __shared__ __align__(16) unsigned short sXl[128 * 40];

  const int t = threadIdx.x;
  const int w = t >> 6, lane = t & 63;
  const int quad = lane >> 4, lr = lane & 15;
  const int row0 = blockIdx.x * 128;
  const int col0 = blockIdx.y * 64;

  // zero the dummy row NN (read by k_aggregate pad slots)
  if (blockIdx.x == 0 && blockIdx.y == 0 && t < 64)
    *(unsigned*)&Hs[(size_t)NN * CH + t * 2] = 0u;

#pragma unroll
  for (int j = 0; j < 8; ++j) {
    int id = t + j * 256;
    int n = id >> 5, kk = (id & 31) * 4;
    *(ushort4*)&sWh[n * 136 + kk] = *(const ushort4*)&wth[(col0 + n) * 128 + kk];
    *(ushort4*)&sWl[n * 136 + kk] = *(const ushort4*)&wtl[(col0 + n) * 128 + kk];
  }

  float4v acc[2][4];
#pragma unroll
  for (int mi = 0; mi < 2; ++mi)
#pragma unroll
    for (int ni = 0; ni < 4; ++ni) acc[mi][ni] = (float4v){0.f, 0.f, 0.f, 0.f};

  for (int ks = 0; ks < 4; ++ks) {
    const int k0 = ks * 32;
    if (ks) __syncthreads();
#pragma unroll
    for (int i = 0; i < 4; ++i) {
      int row = i * 32 + (t >> 3);
      int seg = t & 7;
      int gr = row0 + row;
      float4 xv = {0.f, 0.f, 0.f, 0.f};
      if (gr < NN) xv = *(const float4*)&X[(size_t)gr * CH + k0 + seg * 4];
      ushort4 h, l;
      h.x = f2bf(xv.x); l.x = f2bf(xv.x - bf2f(h.x));
      h.y = f2bf(xv.y); l.y = f2bf(xv.y - bf2f(h.y));
      h.z = f2bf(xv.z); l.z = f2bf(xv.z - bf2f(h.z));
      h.w = f2bf(xv.w); l.w = f2bf(xv.w - bf2f(h.w));
      *(ushort4*)&sXh[row * 40 + seg * 4] = h;
      *(ushort4*)&sXl[row * 40 + seg * 4] = l;
    }
    __syncthreads();

    short8v ah[2], al[2];
#pragma unroll
    for (int mi = 0; mi < 2; ++mi) {
      int r = w * 32 + mi * 16 + lr;
      ah[mi] = *(const short8v*)&sXh[r * 40 + quad * 8];
      al[mi] = *(const short8v*)&sXl[r * 40 + quad * 8];
    }
#pragma unroll
    for (int ni = 0; ni < 4; ++ni) {
      int n = ni * 16 + lr;
      short8v bh = *(const short8v*)&sWh[n * 136 + k0 + quad * 8];
      short8v bl = *(const short8v*)&sWl[n * 136 + k0 + quad * 8];
#pragma unroll
      for (int mi = 0; mi < 2; ++mi) {
        acc[mi][ni] = __builtin_amdgcn_mfma_f32_16x16x32_bf16(ah[mi], bh, acc[mi][ni], 0, 0, 0);
        acc[mi][ni] = __builtin_amdgcn_mfma_f32_16x16x32_bf16(ah[mi], bl, acc[mi][ni], 0, 0, 0);
        acc[mi][ni] = __builtin_amdgcn_mfma_f32_16x16x32_bf16(al[mi], bh, acc[mi][ni], 0, 0, 0);
      }
    }
  }

#pragma unroll
  for (int mi = 0; mi < 2; ++mi) {
#pragma unroll
    for (int r = 0; r < 4; ++r) {
      int grow = row0 + w * 32 + mi * 16 + quad * 4 + r;
      if (grow < NN) {
        float d = dinv[grow];
#pragma unroll
        for (int ni = 0; ni < 4; ++ni)
          Hs[(size_t)grow * CH + col0 + ni * 16 + lr] = f2bf(d * acc[mi][ni][r]);
      }
    }
  }
}

// Layer-2: Hs(bf16) = diag(dinv) * (A_bf16 @ W). A is exact bf16 (lo=0):
// only 2 MFMA terms (AWh + AWl), no conversion in staging, half the reads.
__global__ __launch_bounds__(256) void k_gemm_bf(
    const unsigned short* __restrict__ A, const unsigned short* __restrict__ wth,
    const unsigned short* __restrict__ wtl, const float* __restrict__ dinv,
    unsigned short* __restrict__ Hs) {
  __shared__ __align__(16) unsigned short sWh[64 * 136];
  __shared__ __align__(16) unsigned short sWl[64 * 136];
  __shared__ __align__(16) unsigned short sA[128 * 40];

  const int t = threadIdx.x;
  const int w = t >> 6, lane = t & 63;
  const int quad = lane >> 4, lr = lane & 15;
  const int row0 = blockIdx.x * 128;
  const int col0 = blockIdx.y * 64;

  if (blockIdx.x == 0 && blockIdx.y == 0 && t < 64)
    *(unsigned*)&Hs[(size_t)NN * CH + t * 2] = 0u;

#pragma unroll
  for (int j = 0; j < 8; ++j) {
    int id = t + j * 256;
    int n = id >> 5, kk = (id & 31) * 4;
    *(ushort4*)&sWh[n * 136 + kk] = *(const ushort4*)&wth[(col0 + n) * 128 + kk];
    *(ushort4*)&sWl[n * 136 + kk] = *(const ushort4*)&wtl[(col0 + n) * 128 + kk];
  }

  float4v acc[2][4];
#pragma unroll
  for (int mi = 0; mi < 2; ++mi)
#pragma unroll
    for (int ni = 0; ni < 4; ++ni) acc[mi][ni] = (float4v){0.f, 0.f, 0.f, 0.f};

  for (int ks = 0; ks < 4; ++ks) {
    const int k0 = ks * 32;
    if (ks) __syncthreads();
    // stage A[row0..row0+127][k0..k0+31] bf16: 8 KB, each thread 2x ushort4
#pragma unroll
    for (int i = 0; i < 2; ++i) {
      int id = t + i * 256;          // 512 ushort4 segments
      int row = id >> 2, seg = id & 3;
      int gr = row0 + row;
      ushort4 v = {0, 0, 0, 0};
      if (gr < NN) v = *(const ushort4*)&A[(size_t)gr * CH + k0 + seg * 8];
      *(ushort4*)&sA[row * 40 + seg * 8] = v;
      ushort4 v2 = {0, 0, 0, 0};
      if (gr < NN) v2 = *(const ushort4*)&A[(size_t)gr * CH + k0 + seg * 8 + 4];
      *(ushort4*)&sA[row * 40 + seg * 8 + 4] = v2;
    }
    __syncthreads();

    short8v ah[2];
#pragma unroll
    for (int mi = 0; mi < 2; ++mi) {
      int r = w * 32 + mi * 16 + lr;
      ah[mi] = *(const short8v*)&sA[r * 40 + quad * 8];
    }
#pragma unroll
    for (int ni = 0; ni < 4; ++ni) {
      int n = ni * 16 + lr;
      short8v bh = *(const short8v*)&sWh[n * 136 + k0 + quad * 8];
      short8v bl = *(const short8v*)&sWl[n * 136 + k0 + quad * 8];
#pragma unroll
      for (int mi = 0; mi < 2; ++mi) {
        acc[mi][ni] = __builtin_amdgcn_mfma_f32_16x16x32_bf16(ah[mi], bh, acc[mi][ni], 0, 0, 0);
        acc[mi][ni] = __builtin_amdgcn_mfma_f32_16x16x32_bf16(ah[mi], bl, acc[mi][ni], 0, 0, 0);
      }
    }
  }

#pragma unroll
  for (int mi = 0; mi < 2; ++mi) {
#pragma unroll
    for (int r = 0; r < 4; ++r) {
      int grow = row0 + w * 32 + mi * 16 + quad * 4 + r;
      if (grow < NN) {
        float d = dinv[grow];
#pragma unroll
        for (int ni = 0; ni < 4; ++ni)
          Hs[(size_t)grow * CH + col0 + ni * 16 + lr] = f2bf(d * acc[mi][ni][r]);
      }
    }
  }
}

// out(bf16)[i] = relu(dinv[i]*(Hs[i] + sum Hs[csr[e]]) + b). One wave per node.
// r12 form (verified local optimum) + bf16 packed output (halves WRITE).
__global__ __launch_bounds__(256) void k_aggregate(
    const unsigned* __restrict__ H, const int* __restrict__ rows,
    const int* __restrict__ csr, const float* __restrict__ dinv,
    const float* __restrict__ bias, unsigned* __restrict__ out) {
  int node = blockIdx.x * 4 + (threadIdx.x >> 6);
  int lane = threadIdx.x & 63;
  if (node >= NN) return;
  float bx = bias[2 * lane], by = bias[2 * lane + 1];
  unsigned sv = H[((unsigned)node << 6) | lane];  // self-loop term
  float ax = bflo(sv), ay = bfhi(sv);
  int e0 = rows[node], e1 = rows[node + 1];  // padded, multiple of 8
  if (e1 > e0) {
    unsigned va[8], vb[8];
#pragma unroll
    for (int k = 0; k < 8; ++k)
      va[k] = H[((unsigned)csr[e0 + k] << 6) | lane];
    for (int base = e0 + 8; base < e1; base += 8) {
#pragma unroll
      for (int k = 0; k < 8; ++k)
        vb[k] = H[((unsigned)csr[base + k] << 6) | lane];
#pragma unroll
      for (int k = 0; k < 8; ++k) { ax += bflo(va[k]); ay += bfhi(va[k]); }
#pragma unroll
      for (int k = 0; k < 8; ++k) va[k] = vb[k];
    }
#pragma unroll
    for (int k = 0; k < 8; ++k) { ax += bflo(va[k]); ay += bfhi(va[k]); }
  }
  float d = dinv[node];
  float ox = fmaxf(fmaf(d, ax, bx), 0.f);
  float oy = fmaxf(fmaf(d, ay, by), 0.f);
  out[((unsigned)node << 6) | lane] = pack2(ox, oy);
}

// Fused per-graph pipeline: segmented mean pool (bf16 A) -> MLP1 -> MLP2 -> out.
__global__ __launch_bounds__(256) void k_head(
    const unsigned short* __restrict__ A, const int* __restrict__ start,
    const float* __restrict__ W3, const float* __restrict__ b3,
    const float* __restrict__ W4, const float* __restrict__ b4,
    float* __restrict__ out) {
  __shared__ float pooled[128];
  __shared__ float part[128];
  __shared__ float g1[128];
  int g = blockIdx.x;
  int c = threadIdx.x & 127;
  int half = threadIdx.x >> 7;
  int s0 = start[g], s1 = start[g + 1];
  float sum = 0.f;
  for (int i = s0 + half; i < s1; i += 2)
    sum += bf2f(A[(size_t)i * CH + c]);
  if (half) part[c] = sum;
  __syncthreads();
  if (!half) {
    float n = fmaxf((float)(s1 - s0), 1.0f);
    pooled[c] = (sum + part[c]) / n;
  }
  __syncthreads();
  if (threadIdx.x < 128) {
    float acc = b3[c];
    for (int k = 0; k < 128; ++k) acc += pooled[k] * W3[k * CH + c];
    g1[c] = fmaxf(acc, 0.f);
  }
  __syncthreads();
  if (threadIdx.x < 64) {
    float acc = b4[threadIdx.x];
    for (int k = 0; k < 128; ++k) acc += g1[k] * W4[k * OC + threadIdx.x];
    out[(size_t)g * OC + threadIdx.x] = acc;
  }
}

extern "C" void kernel_launch(void* const* d_in, const int* in_sizes, int n_in,
                              void* d_out, int out_size, void* d_ws, size_t ws_size,
                              hipStream_t stream) {
  const float* X   = (const float*)d_in[0];
  const int* ei    = (const int*)d_in[1];
  const int* batch = (const int*)d_in[2];
  const float* W1  = (const float*)d_in[3];
  const float* b1  = (const float*)d_in[4];
  const float* W2  = (const float*)d_in[5];
  const float* b2  = (const float*)d_in[6];
  const float* W3  = (const float*)d_in[7];
  const float* b3  = (const float*)d_in[8];
  const float* W4  = (const float*)d_in[9];
  const float* b4  = (const float*)d_in[10];
  float* out = (float*)d_out;
  float* ws = (float*)d_ws;

  const int* src = ei;        // edge_index[0]
  const int* dst = ei + EE;   // edge_index[1]

  float* dinv = ws + O_DINV;
  int* rows   = (int*)(ws + O_ROWS);
  int* cnt    = (int*)(ws + O_CNT);
  int* part   = (int*)(ws + O_PART);
  int* offs   = (int*)(ws + O_OFFS);
  int* start  = (int*)(ws + O_START);
  int* csr    = (int*)(ws + O_CSR);
  unsigned short* Hs = (unsigned short*)(ws + O_HS);
  unsigned* stg = (unsigned*)(ws + O_STG);
  unsigned short* wt1 = (unsigned short*)(ws + O_WT1);
  unsigned short* wt2 = (unsigned short*)(ws + O_WT2);
  unsigned short* A1 = (unsigned short*)(ws + O_A1);

  k_part<<<PBLK, 1024, 0, stream>>>(src, dst, cnt, stg);
  k_count<<<NCB, 1024, 0, stream>>>(stg, cnt, rows, part, dinv);
  k_scan_part<<<1, 128, 0, stream>>>(part, offs);
  k_scan_add<<<(NN + 255) / 256, 256, 0, stream>>>(rows, offs, part, batch, start);
  k_place<<<NCB, 1024, 0, stream>>>(stg, cnt, rows, csr);
  // after k_place the staging region is dead; wt1/wt2 overwrite its start
  k_wsplit<<<128, 256, 0, stream>>>(W1, W2, wt1, wt2);

  dim3 ggrid((NN + 127) / 128, 2);
  // layer 1 (fp32 X input, 3-term split MFMA)
  k_gemm_mfma<<<ggrid, 256, 0, stream>>>(X, wt1, wt1 + 16384, dinv, Hs);
  k_aggregate<<<(NN + 3) / 4, 256, 0, stream>>>((const unsigned*)Hs, rows, csr, dinv, b1, (unsigned*)A1);
  // layer 2 (bf16 A1 input, 2-term MFMA)
  k_gemm_bf<<<ggrid, 256, 0, stream>>>(A1, wt2, wt2 + 16384, dinv, Hs);
  k_aggregate<<<(NN + 3) / 4, 256, 0, stream>>>((const unsigned*)Hs, rows, csr, dinv, b2, (unsigned*)A1);

  k_head<<<NG, 256, 0, stream>>>(A1, start, W3, b3, W4, b4, out);
}